// Round 4
// baseline (433.918 us; speedup 1.0000x reference)
//
#include <hip/hip_runtime.h>
#include <cstdint>
#include <cstddef>

// Problem constants: B=32, N=2048, L=128, D=1024, V=32000
#define BATCH 32
#define NROW  2048
#define LTOK  128
#define DDIM  1024

#define NSTG  16       // Y column stages
#define SCOL  64       // cols per stage (bf16): 128 rows x 64 cols = 16 KB/buffer

typedef short s8v  __attribute__((ext_vector_type(8)));
typedef float f4v  __attribute__((ext_vector_type(4)));

// Truncation-pack two fp32 -> packed bf16 pair in ONE v_perm_b32.
__device__ __forceinline__ uint32_t pk2(float lo, float hi) {
    return __builtin_amdgcn_perm(__float_as_uint(hi), __float_as_uint(lo), 0x07060302u);
}

// ---------------- Pre-pass: gather + bf16-convert targets, compute y2 ----------------
__global__ __launch_bounds__(256)
void prep_y(const int*   __restrict__ tok,   // [B, L]
            const float* __restrict__ E,     // [V, D]
            uint32_t*    __restrict__ Ybf,   // [B*L*D/2] packed bf16 pairs
            float*       __restrict__ y2)    // [B*L]
{
    const int l = blockIdx.x, b = blockIdx.y;
    const int tid = threadIdx.x;               // 256 threads, 4 floats each
    const int t = tok[b * LTOK + l];
    const float4 v = ((const float4*)(E + (size_t)t * DDIM))[tid];
    float s = v.x*v.x + v.y*v.y + v.z*v.z + v.w*v.w;
    uint2 p; p.x = pk2(v.x, v.y); p.y = pk2(v.z, v.w);
    ((uint2*)(Ybf + ((size_t)(b * LTOK + l) * DDIM) / 2))[tid] = p;
#pragma unroll
    for (int o = 1; o < 64; o <<= 1) s += __shfl_xor(s, o);
    __shared__ float ws4[4];
    if ((tid & 63) == 0) ws4[tid >> 6] = s;
    __syncthreads();
    if (tid == 0) y2[b * LTOK + l] = ws4[0] + ws4[1] + ws4[2] + ws4[3];
}

// ---------------- Main kernel ----------------
// Y-stationary, double-buffered 64-col LDS stages, counted-vmcnt barriers
// (T3/T4), X direct-to-registers distance-3 pipeline, XCD-swizzled grid.
__global__ __launch_bounds__(256, 4)
void cdist_min_mean_kernel(const float* __restrict__ X,     // [B, N, D] fp32
                           const short* __restrict__ Ybf,   // [B, L, D] bf16
                           const float* __restrict__ y2g,   // [B, L]
                           float* __restrict__ out)
{
    __shared__ __align__(16) short Ys[2][LTOK * SCOL];   // 2 x 16 KB, XOR-swizzled
    __shared__ float x2s[64];
    __shared__ float rowmin[64];

    const int tid  = threadIdx.x;
    const int lane = tid & 63;
    const int wid  = tid >> 6;
    const int quad = lane >> 4;
    const int l15  = lane & 15;
    const int rxor = l15 & 7;

    // Bijective XCD swizzle: 1024 blocks, 8 XCDs -> 128 contiguous blocks
    // (= 4 whole batches) per XCD, so each XCD's L2 holds only 4 Y panels (1 MB).
    const int linear  = blockIdx.y * gridDim.x + blockIdx.x;   // 0..1023
    const int newlin  = (linear & 7) * 128 + (linear >> 3);
    const int b       = newlin >> 5;
    const int rowBase = (newlin & 31) * 64;

    // X per-thread pointer in A-frag layout: row = rowBase+wid*16+l15, col chunk quad*8
    const float* xptr = X + ((size_t)b * NROW + rowBase + wid * 16 + l15) * DDIM + quad * 8;

    // Y stage source pointers (per lane), issue i=0..3:
    // dest slot = i*256 + wid*64 + lane (16 B slots, linear) -> row = i*32+wid*8+(lane>>3),
    // stored chunk = lane&7; XOR swizzle: source chunk = (lane&7) ^ (lane>>3).
    const short* ysrc[4];
#pragma unroll
    for (int i = 0; i < 4; ++i)
        ysrc[i] = Ybf + ((size_t)b * LTOK + i * 32 + wid * 8 + (lane >> 3)) * DDIM
                + (((lane & 7) ^ (lane >> 3)) << 3);

    f4v acc[8];
#pragma unroll
    for (int ni = 0; ni < 8; ++ni) acc[ni] = (f4v){0.f, 0.f, 0.f, 0.f};
    float xacc = 0.f;

    float4 pa[4], pb[4];

    auto stage = [&](int st, int buf) {
#pragma unroll
        for (int i = 0; i < 4; ++i)
            __builtin_amdgcn_global_load_lds(
                (const __attribute__((address_space(1))) void*)(ysrc[i] + st * SCOL),
                (__attribute__((address_space(3))) void*)&Ys[buf][(i * 256 + (wid << 6)) * 8],
                16, 0, 0);
    };

    auto chunk = [&](int t, int buf) {
        // pack chunk t (slot t&3) -> A-frag; exact fp32 sumsq on the fly
        const float4 a = pa[t & 3], c = pb[t & 3];
        xacc += a.x*a.x + a.y*a.y + a.z*a.z + a.w*a.w
              + c.x*c.x + c.y*c.y + c.z*c.z + c.w*c.w;
        uint4 p;
        p.x = pk2(a.x, a.y); p.y = pk2(a.z, a.w);
        p.z = pk2(c.x, c.y); p.w = pk2(c.z, c.w);
        s8v af;
        __builtin_memcpy(&af, &p, 16);

        if (t + 3 < 32) {                            // distance-3 X prefetch
            pa[(t + 3) & 3] = *(const float4*)(xptr + (t + 3) * 32);
            pb[(t + 3) & 3] = *(const float4*)(xptr + (t + 3) * 32 + 4);
        }

        const int t2 = t & 1;                        // 32-col chunk within stage
#pragma unroll
        for (int ni = 0; ni < 8; ++ni) {
            const s8v bf = *(const s8v*)&Ys[buf][(ni * 16 + l15) * SCOL
                                                + (((t2 * 4 + quad) ^ rxor) << 3)];
            acc[ni] = __builtin_amdgcn_mfma_f32_16x16x32_bf16(af, bf, acc[ni], 0, 0, 0);
        }
    };

    // Prologue: stage 0 -> buf 0; X chunks 0..2 in flight; drain stage only (vmcnt(6)).
    stage(0, 0);
#pragma unroll
    for (int t = 0; t < 3; ++t) {
        pa[t] = *(const float4*)(xptr + t * 32);
        pb[t] = *(const float4*)(xptr + t * 32 + 4);
    }
    __builtin_amdgcn_sched_barrier(0);
    asm volatile("s_waitcnt vmcnt(6)" ::: "memory");   // 6 X loads newer than stage
    __builtin_amdgcn_s_barrier();

#pragma unroll
    for (int st = 0; st < NSTG; ++st) {
        const int buf = st & 1;
        if (st < NSTG - 1) stage(st + 1, buf ^ 1);     // issue next stage FIRST
        chunk(2 * st,     buf);
        chunk(2 * st + 1, buf);
        if (st < NSTG - 1) {
            __builtin_amdgcn_sched_barrier(0);
            // Counted drain: only the X prefetches issued AFTER the stage loads
            // may remain in flight (4 normally; 2 at st=14 where prefetch(32) is skipped).
            if (st == NSTG - 2) asm volatile("s_waitcnt vmcnt(2)" ::: "memory");
            else                asm volatile("s_waitcnt vmcnt(4)" ::: "memory");
            __builtin_amdgcn_s_barrier();
        }
    }

    // x2: thread holds partial over its 256 cols of row (wid*16+l15); reduce over quads
    {
        float s = xacc;
        s += __shfl_xor(s, 16);
        s += __shfl_xor(s, 32);
        if (lane < 16) x2s[wid * 16 + lane] = s;
    }

    // rowmin: C/D layout col=l15, row=quad*4+j. min over 8 ni frags + 16 lanes.
    float y2r[8];
#pragma unroll
    for (int ni = 0; ni < 8; ++ni)
        y2r[ni] = y2g[b * LTOK + ni * 16 + l15];

#pragma unroll
    for (int j = 0; j < 4; ++j) {
        float m = y2r[0] - 2.f * acc[0][j];
#pragma unroll
        for (int ni = 1; ni < 8; ++ni)
            m = fminf(m, y2r[ni] - 2.f * acc[ni][j]);
        m = fminf(m, __shfl_xor(m, 1));
        m = fminf(m, __shfl_xor(m, 2));
        m = fminf(m, __shfl_xor(m, 4));
        m = fminf(m, __shfl_xor(m, 8));
        if (l15 == 0) rowmin[wid * 16 + quad * 4 + j] = m;
    }
    __syncthreads();

    if (tid < 64) {                                  // wave 0: final reduce over 64 rows
        float part = sqrtf(fmaxf(x2s[tid] + rowmin[tid], 0.f));
#pragma unroll
        for (int s = 1; s < 64; s <<= 1) part += __shfl_xor(part, s);
        if (tid == 0)
            atomicAdd(out, part * (1.0f / (float)(BATCH * NROW)));
    }
}

extern "C" void kernel_launch(void* const* d_in, const int* in_sizes, int n_in,
                              void* d_out, int out_size, void* d_ws, size_t ws_size,
                              hipStream_t stream) {
    const float* X   = (const float*)d_in[0];  // image_features [B,N,D] fp32
    const int*   tok = (const int*)d_in[1];    // token_ids [B,L] int32
    const float* E   = (const float*)d_in[2];  // emb_table [V,D] fp32
    float* out = (float*)d_out;

    // ws layout: [0, 8MB) Ybf bf16, [8MB, +16KB) y2 fp32
    uint32_t* Ybf = (uint32_t*)d_ws;
    float*    y2  = (float*)((char*)d_ws + (size_t)BATCH * LTOK * DDIM * 2);

    hipMemsetAsync(out, 0, sizeof(float), stream);

    dim3 pgrid(LTOK, BATCH, 1);
    prep_y<<<pgrid, 256, 0, stream>>>(tok, E, Ybf, y2);

    dim3 grid(NROW / 64, BATCH, 1);   // 32 x 32 = 1024 blocks -> 4 blocks/CU
    cdist_min_mean_kernel<<<grid, 256, 0, stream>>>(X, (const short*)Ybf, y2, out);
}